// Round 4
// baseline (468.915 us; speedup 1.0000x reference)
//
#include <hip/hip_runtime.h>
#include <hip/hip_bf16.h>

// B=8192, N=M=K=2048, H=10.
// Pipeline (4 launches):
//   1) pre_kernel: fused [col-sum partials] + [row sums] + [X -> Xh,Xl bf16 split]
//      (reduction blocks scheduled FIRST to hide their latency tail)
//   2) nca_update: finish col sums inline, per-cell MLP, write TRANSPOSED bf16
//      split Bth/Btl [M][N]
//   3) 3-term bf16 MFMA GEMM, lane-major fragment-packed LDS (conflict-free)
//   4) row softmax in place (wave-shuffle reductions)

typedef short short8 __attribute__((ext_vector_type(8)));
typedef float floatx4 __attribute__((ext_vector_type(4)));

#define GK 2048
#define NROWS 2048
#define MCOLS 2048
#define NCHUNK 16

__device__ inline unsigned short f2bf_rne(float x) {
  unsigned u = __float_as_uint(x);
  unsigned r = (u + 0x7fffu + ((u >> 16) & 1u)) >> 16;
  return (unsigned short)r;
}
__device__ inline float bf2f(unsigned short h) {
  return __uint_as_float(((unsigned)h) << 16);
}

// ---------------- fused pre-pass --------------------------------------------
// blocks [0, 128)            : col-sum partials (16 chunks x 8 col-blocks)
// blocks [128, 128+2048)     : row sums of weight (1 row per block)
// blocks [2176, 2176+16384)  : X -> Xh/Xl split (1 float4 per thread)
#define CS_BLOCKS 128
#define RS_BLOCKS 2048
__global__ __launch_bounds__(256) void pre_kernel(
    const float* __restrict__ X, const float* __restrict__ W,
    unsigned short* __restrict__ Xh, unsigned short* __restrict__ Xl,
    float* __restrict__ part, float* __restrict__ rowS) {
  const int bid = blockIdx.x;
  const int tid = threadIdx.x;

  if (bid < CS_BLOCKS) {
    int chunk = bid >> 3;                 // 0..15
    int j = (bid & 7) * 256 + tid;        // column
    int i0 = chunk * (NROWS / NCHUNK);
    float s = 0.f;
    for (int i = i0; i < i0 + NROWS / NCHUNK; ++i) s += W[(size_t)i * MCOLS + j];
    part[(size_t)chunk * MCOLS + j] = s;
  } else if (bid < CS_BLOCKS + RS_BLOCKS) {
    int row = bid - CS_BLOCKS;
    const float4* p = (const float4*)(W + (size_t)row * MCOLS);
    float4 a = p[tid];
    float4 b = p[tid + 256];
    float v = (a.x + a.y) + (a.z + a.w) + (b.x + b.y) + (b.z + b.w);
    __shared__ float red[256];
    red[tid] = v;
    __syncthreads();
    for (int s = 128; s > 0; s >>= 1) {
      if (tid < s) red[tid] += red[tid + s];
      __syncthreads();
    }
    if (tid == 0) rowS[row] = red[0];
  } else {
    size_t i = (size_t)(bid - CS_BLOCKS - RS_BLOCKS) * 256 + tid;
    float4 v = ((const float4*)X)[i];
    ushort4 h, l;
    h.x = f2bf_rne(v.x); l.x = f2bf_rne(v.x - bf2f(h.x));
    h.y = f2bf_rne(v.y); l.y = f2bf_rne(v.y - bf2f(h.y));
    h.z = f2bf_rne(v.z); l.z = f2bf_rne(v.z - bf2f(h.z));
    h.w = f2bf_rne(v.w); l.w = f2bf_rne(v.w - bf2f(h.w));
    ((ushort4*)Xh)[i] = h;
    ((ushort4*)Xl)[i] = l;
  }
}

// ------- NCA MLP -> new_weight, transposed bf16 split out -------------------
__global__ __launch_bounds__(256) void nca_update_kernel(
    const float* __restrict__ W, const float* __restrict__ part,
    const float* __restrict__ rowS,
    const float* __restrict__ W1, const float* __restrict__ b1,
    const float* __restrict__ W2, const float* __restrict__ b2,
    const float* __restrict__ W3, const float* __restrict__ b3,
    unsigned short* __restrict__ Bth, unsigned short* __restrict__ Btl) {
  __shared__ float sW1[30], sb1[10], sW2[100], sb2[10], sW3[10], sb3;
  __shared__ float sColS[32];
  __shared__ float cred[NCHUNK][33];
  __shared__ unsigned short Th[32][33], Tl[32][33];
  const int tid = threadIdx.x;
  const int i0 = blockIdx.y * 32;
  const int j0 = blockIdx.x * 32;

  if (tid < 30) sW1[tid] = W1[tid];
  if (tid < 10) { sb1[tid] = b1[tid]; sb2[tid] = b2[tid]; sW3[tid] = W3[tid]; }
  if (tid >= 32 && tid < 132) sW2[tid - 32] = W2[tid - 32];
  if (tid == 0) sb3 = b3[0];

  // finish column sums for this block's 32 columns (16 partials each)
  {
    int ch = tid >> 5;       // 0..7
    int jl = tid & 31;
    cred[ch][jl]     = part[(size_t)ch * MCOLS + j0 + jl];
    cred[ch + 8][jl] = part[(size_t)(ch + 8) * MCOLS + j0 + jl];
  }
  __syncthreads();
  if (tid < 32) {
    float s = 0.f;
#pragma unroll
    for (int c = 0; c < NCHUNK; ++c) s += cred[c][tid];
    sColS[tid] = s;
  }
  __syncthreads();

  const int r = tid >> 5;   // 0..7
  const int c = tid & 31;   // 0..31

  float w[4], fwd[4], bwd[4];
#pragma unroll
  for (int cell = 0; cell < 4; ++cell) {
    int il = r + 8 * cell;
    float wv = W[(size_t)(i0 + il) * MCOLS + j0 + c];
    w[cell] = wv;
    fwd[cell] = (sColS[c] - wv) * (1.0f / (float)(NROWS - 1));
    bwd[cell] = (rowS[i0 + il] - wv) * (1.0f / (float)(MCOLS - 1));
  }

  float h1[4][10];
#pragma unroll
  for (int o = 0; o < 10; ++o) {
    float w1a = sW1[o], w1b = sW1[10 + o], w1c = sW1[20 + o], bb = sb1[o];
#pragma unroll
    for (int cell = 0; cell < 4; ++cell) {
      float v = fmaf(w[cell], w1a, fmaf(fwd[cell], w1b, fmaf(bwd[cell], w1c, bb)));
      h1[cell][o] = fmaxf(v, 0.f);
    }
  }
  float u[4] = {sb3, sb3, sb3, sb3};
#pragma unroll
  for (int o = 0; o < 10; ++o) {
    float h2[4];
    float bb = sb2[o];
#pragma unroll
    for (int cell = 0; cell < 4; ++cell) h2[cell] = bb;
#pragma unroll
    for (int p = 0; p < 10; ++p) {
      float wv = sW2[p * 10 + o];
#pragma unroll
      for (int cell = 0; cell < 4; ++cell) h2[cell] = fmaf(h1[cell][p], wv, h2[cell]);
    }
    float w3 = sW3[o];
#pragma unroll
    for (int cell = 0; cell < 4; ++cell) u[cell] = fmaf(fmaxf(h2[cell], 0.f), w3, u[cell]);
  }

#pragma unroll
  for (int cell = 0; cell < 4; ++cell) {
    int il = r + 8 * cell;
    float nw = w[cell] + u[cell];
    unsigned short hb = f2bf_rne(nw);
    Th[il][c] = hb;
    Tl[il][c] = f2bf_rne(nw - bf2f(hb));
  }
  __syncthreads();

#pragma unroll
  for (int cell = 0; cell < 4; ++cell) {
    int jl = r + 8 * cell;
    size_t oidx = (size_t)(j0 + jl) * NROWS + i0 + c;
    Bth[oidx] = Th[c][jl];
    Btl[oidx] = Tl[c][jl];
  }
}

// ---------------- 3-term bf16 MFMA GEMM -------------------------------------
// Lane-major fragment-packed LDS: each 16-row block R is 64 slots of 16B;
// slot l holds A[row=R*16+(l&15)][kgroup=(l>>4)] (8 bf16). Fragment reads are
// base + lane*16 -> consecutive lanes, consecutive addresses: conflict-free.
// Staging permutes the per-lane GLOBAL address (legal; LDS dest stays linear).
__global__ __launch_bounds__(256) void gemm_kernel(
    const unsigned short* __restrict__ Xh, const unsigned short* __restrict__ Xl,
    const unsigned short* __restrict__ Bth, const unsigned short* __restrict__ Btl,
    float* __restrict__ C) {
  __shared__ short sAh[128 * 32];
  __shared__ short sAl[128 * 32];
  __shared__ short sBh[128 * 32];
  __shared__ short sBl[128 * 32];

  const int tid = threadIdx.x;
  const int lane = tid & 63;
  const int wave = tid >> 6;
  const int wr = wave >> 1;
  const int wc = wave & 1;
  const int fm = lane & 15;
  const int q = lane >> 4;

  const int bx = blockIdx.x;
  const int by = blockIdx.y;

  const unsigned short* A0h = Xh + (size_t)(by * 128) * GK;
  const unsigned short* A0l = Xl + (size_t)(by * 128) * GK;
  const unsigned short* B0h = Bth + (size_t)(bx * 128) * GK;
  const unsigned short* B0l = Btl + (size_t)(bx * 128) * GK;

  // staging: lane l fetches [row = R*16 + (l&15)][k = k0 + (l>>4)*8 ..+8)
  const int frow = fm;
  const int fko = q * 8;

  floatx4 acc[4][4];
#pragma unroll
  for (int i = 0; i < 4; ++i)
#pragma unroll
    for (int j = 0; j < 4; ++j) acc[i][j] = (floatx4){0.f, 0.f, 0.f, 0.f};

  for (int k0 = 0; k0 < GK; k0 += 32) {
#pragma unroll
    for (int r = 0; r < 2; ++r) {
      int R = wave * 2 + r;                       // row-block 0..7
      size_t goff = (size_t)(R * 16 + frow) * GK + k0 + fko;
      int ldsoff = R * 512;                       // shorts (1KB per block)
      __builtin_amdgcn_global_load_lds(
          (const __attribute__((address_space(1))) void*)(A0h + goff),
          (__attribute__((address_space(3))) void*)(sAh + ldsoff), 16, 0, 0);
      __builtin_amdgcn_global_load_lds(
          (const __attribute__((address_space(1))) void*)(A0l + goff),
          (__attribute__((address_space(3))) void*)(sAl + ldsoff), 16, 0, 0);
      __builtin_amdgcn_global_load_lds(
          (const __attribute__((address_space(1))) void*)(B0h + goff),
          (__attribute__((address_space(3))) void*)(sBh + ldsoff), 16, 0, 0);
      __builtin_amdgcn_global_load_lds(
          (const __attribute__((address_space(1))) void*)(B0l + goff),
          (__attribute__((address_space(3))) void*)(sBl + ldsoff), 16, 0, 0);
    }
    __syncthreads();

    short8 ah[4], al[4], bh[4], bl[4];
#pragma unroll
    for (int mi = 0; mi < 4; ++mi) {
      int off = (wr * 4 + mi) * 512 + lane * 8;   // conflict-free
      ah[mi] = *(const short8*)(sAh + off);
      al[mi] = *(const short8*)(sAl + off);
    }
#pragma unroll
    for (int ni = 0; ni < 4; ++ni) {
      int off = (wc * 4 + ni) * 512 + lane * 8;
      bh[ni] = *(const short8*)(sBh + off);
      bl[ni] = *(const short8*)(sBl + off);
    }
#pragma unroll
    for (int mi = 0; mi < 4; ++mi)
#pragma unroll
      for (int ni = 0; ni < 4; ++ni) {
        acc[mi][ni] = __builtin_amdgcn_mfma_f32_16x16x32_bf16(ah[mi], bh[ni], acc[mi][ni], 0, 0, 0);
        acc[mi][ni] = __builtin_amdgcn_mfma_f32_16x16x32_bf16(al[mi], bh[ni], acc[mi][ni], 0, 0, 0);
        acc[mi][ni] = __builtin_amdgcn_mfma_f32_16x16x32_bf16(ah[mi], bl[ni], acc[mi][ni], 0, 0, 0);
      }
    __syncthreads();
  }

#pragma unroll
  for (int mi = 0; mi < 4; ++mi)
#pragma unroll
    for (int ni = 0; ni < 4; ++ni) {
      int col = bx * 128 + wc * 64 + ni * 16 + fm;
#pragma unroll
      for (int r = 0; r < 4; ++r) {
        int row = by * 128 + wr * 64 + mi * 16 + q * 4 + r;
        C[(size_t)row * 2048 + col] = acc[mi][ni][r];
      }
    }
}

// ---------------- row softmax in place (wave-shuffle reductions) ------------
__global__ __launch_bounds__(256) void softmax_kernel(float* __restrict__ C) {
  const int row = blockIdx.x;
  const int tid = threadIdx.x;
  const int lane = tid & 63;
  const int wv = tid >> 6;
  float4* p = (float4*)(C + (size_t)row * MCOLS);
  float4 a = p[tid];
  float4 b = p[tid + 256];

  __shared__ float wmax[4], wsum[4];

  float vmax = fmaxf(fmaxf(fmaxf(a.x, a.y), fmaxf(a.z, a.w)),
                     fmaxf(fmaxf(b.x, b.y), fmaxf(b.z, b.w)));
#pragma unroll
  for (int off = 32; off > 0; off >>= 1)
    vmax = fmaxf(vmax, __shfl_xor(vmax, off));
  if (lane == 0) wmax[wv] = vmax;
  __syncthreads();
  float m = fmaxf(fmaxf(wmax[0], wmax[1]), fmaxf(wmax[2], wmax[3]));

  float e[8];
  e[0] = __expf(a.x - m); e[1] = __expf(a.y - m); e[2] = __expf(a.z - m); e[3] = __expf(a.w - m);
  e[4] = __expf(b.x - m); e[5] = __expf(b.y - m); e[6] = __expf(b.z - m); e[7] = __expf(b.w - m);
  float sum = ((e[0] + e[1]) + (e[2] + e[3])) + ((e[4] + e[5]) + (e[6] + e[7]));
#pragma unroll
  for (int off = 32; off > 0; off >>= 1)
    sum += __shfl_xor(sum, off);
  if (lane == 0) wsum[wv] = sum;
  __syncthreads();
  float inv = 1.0f / (((wsum[0] + wsum[1]) + (wsum[2] + wsum[3])));

  a = make_float4(e[0] * inv, e[1] * inv, e[2] * inv, e[3] * inv);
  b = make_float4(e[4] * inv, e[5] * inv, e[6] * inv, e[7] * inv);
  p[tid] = a;
  p[tid + 256] = b;
}

// ---------------- launcher --------------------------------------------------
extern "C" void kernel_launch(void* const* d_in, const int* in_sizes, int n_in,
                              void* d_out, int out_size, void* d_ws, size_t ws_size,
                              hipStream_t stream) {
  const float* X      = (const float*)d_in[0];
  const float* weight = (const float*)d_in[1];
  const float* W1     = (const float*)d_in[2];
  const float* b1     = (const float*)d_in[3];
  const float* W2     = (const float*)d_in[4];
  const float* b2     = (const float*)d_in[5];
  const float* W3     = (const float*)d_in[6];
  const float* b3     = (const float*)d_in[7];
  float* out = (float*)d_out;

  const int N = 2048, M = 2048;
  const int Bdim = in_sizes[0] / N;   // 8192

  // workspace: rowS[2048] part[16*2048] (fp32) | Xh Xl [B*N] | Bth Btl [M*N] (ushort)
  float* rowS = (float*)d_ws;
  float* part = rowS + 2048;
  unsigned short* Xh  = (unsigned short*)(part + NCHUNK * 2048);
  unsigned short* Xl  = Xh + (size_t)Bdim * N;
  unsigned short* Bth = Xl + (size_t)Bdim * N;
  unsigned short* Btl = Bth + (size_t)M * N;

  const int conv_blocks = (Bdim * N) / 4 / 256;  // 16384
  pre_kernel<<<CS_BLOCKS + RS_BLOCKS + conv_blocks, 256, 0, stream>>>(
      X, weight, Xh, Xl, part, rowS);

  nca_update_kernel<<<dim3(M / 32, N / 32), 256, 0, stream>>>(
      weight, part, rowS, W1, b1, W2, b2, W3, b3, Bth, Btl);

  gemm_kernel<<<dim3(M / 128, Bdim / 128), 256, 0, stream>>>(Xh, Xl, Bth, Btl, out);

  softmax_kernel<<<Bdim, 256, 0, stream>>>(out);
}

// Round 5
// 388.942 us; speedup vs baseline: 1.2056x; 1.2056x over previous
//
#include <hip/hip_runtime.h>
#include <hip/hip_bf16.h>

// B=8192, N=M=K=2048, H=10.
// Pipeline (4 launches):
//   1) pre_kernel: fused [col-sum partials] + [row sums] + [X -> Xh,Xl bf16 split]
//   2) nca_update: finish col sums inline, per-cell MLP, write TRANSPOSED bf16
//      split Bth/Btl [M][N]
//   3) 3-term bf16 MFMA GEMM, XOR-swizzled LDS:
//      staging stays quad-contiguous in GLOBAL (4 lanes = 64B segment, round-3
//      coalescing) while the k-chunk is XOR'd so fragment ds_read_b128 is
//      2-way-max bank aliased (free).
//   4) row softmax in place (wave-shuffle reductions)

typedef short short8 __attribute__((ext_vector_type(8)));
typedef float floatx4 __attribute__((ext_vector_type(4)));

#define GK 2048
#define NROWS 2048
#define MCOLS 2048
#define NCHUNK 16

__device__ inline unsigned short f2bf_rne(float x) {
  unsigned u = __float_as_uint(x);
  unsigned r = (u + 0x7fffu + ((u >> 16) & 1u)) >> 16;
  return (unsigned short)r;
}
__device__ inline float bf2f(unsigned short h) {
  return __uint_as_float(((unsigned)h) << 16);
}

// ---------------- fused pre-pass --------------------------------------------
#define CS_BLOCKS 128
#define RS_BLOCKS 2048
__global__ __launch_bounds__(256) void pre_kernel(
    const float* __restrict__ X, const float* __restrict__ W,
    unsigned short* __restrict__ Xh, unsigned short* __restrict__ Xl,
    float* __restrict__ part, float* __restrict__ rowS) {
  const int bid = blockIdx.x;
  const int tid = threadIdx.x;

  if (bid < CS_BLOCKS) {
    int chunk = bid >> 3;                 // 0..15
    int j = (bid & 7) * 256 + tid;        // column
    int i0 = chunk * (NROWS / NCHUNK);
    float s = 0.f;
    for (int i = i0; i < i0 + NROWS / NCHUNK; ++i) s += W[(size_t)i * MCOLS + j];
    part[(size_t)chunk * MCOLS + j] = s;
  } else if (bid < CS_BLOCKS + RS_BLOCKS) {
    int row = bid - CS_BLOCKS;
    const float4* p = (const float4*)(W + (size_t)row * MCOLS);
    float4 a = p[tid];
    float4 b = p[tid + 256];
    float v = (a.x + a.y) + (a.z + a.w) + (b.x + b.y) + (b.z + b.w);
    __shared__ float red[256];
    red[tid] = v;
    __syncthreads();
    for (int s = 128; s > 0; s >>= 1) {
      if (tid < s) red[tid] += red[tid + s];
      __syncthreads();
    }
    if (tid == 0) rowS[row] = red[0];
  } else {
    size_t i = (size_t)(bid - CS_BLOCKS - RS_BLOCKS) * 256 + tid;
    float4 v = ((const float4*)X)[i];
    ushort4 h, l;
    h.x = f2bf_rne(v.x); l.x = f2bf_rne(v.x - bf2f(h.x));
    h.y = f2bf_rne(v.y); l.y = f2bf_rne(v.y - bf2f(h.y));
    h.z = f2bf_rne(v.z); l.z = f2bf_rne(v.z - bf2f(h.z));
    h.w = f2bf_rne(v.w); l.w = f2bf_rne(v.w - bf2f(h.w));
    ((ushort4*)Xh)[i] = h;
    ((ushort4*)Xl)[i] = l;
  }
}

// ------- NCA MLP -> new_weight, transposed bf16 split out -------------------
__global__ __launch_bounds__(256) void nca_update_kernel(
    const float* __restrict__ W, const float* __restrict__ part,
    const float* __restrict__ rowS,
    const float* __restrict__ W1, const float* __restrict__ b1,
    const float* __restrict__ W2, const float* __restrict__ b2,
    const float* __restrict__ W3, const float* __restrict__ b3,
    unsigned short* __restrict__ Bth, unsigned short* __restrict__ Btl) {
  __shared__ float sW1[30], sb1[10], sW2[100], sb2[10], sW3[10], sb3;
  __shared__ float sColS[32];
  __shared__ float cred[NCHUNK][33];
  __shared__ unsigned short Th[32][33], Tl[32][33];
  const int tid = threadIdx.x;
  const int i0 = blockIdx.y * 32;
  const int j0 = blockIdx.x * 32;

  if (tid < 30) sW1[tid] = W1[tid];
  if (tid < 10) { sb1[tid] = b1[tid]; sb2[tid] = b2[tid]; sW3[tid] = W3[tid]; }
  if (tid >= 32 && tid < 132) sW2[tid - 32] = W2[tid - 32];
  if (tid == 0) sb3 = b3[0];

  {
    int ch = tid >> 5;
    int jl = tid & 31;
    cred[ch][jl]     = part[(size_t)ch * MCOLS + j0 + jl];
    cred[ch + 8][jl] = part[(size_t)(ch + 8) * MCOLS + j0 + jl];
  }
  __syncthreads();
  if (tid < 32) {
    float s = 0.f;
#pragma unroll
    for (int c = 0; c < NCHUNK; ++c) s += cred[c][tid];
    sColS[tid] = s;
  }
  __syncthreads();

  const int r = tid >> 5;
  const int c = tid & 31;

  float w[4], fwd[4], bwd[4];
#pragma unroll
  for (int cell = 0; cell < 4; ++cell) {
    int il = r + 8 * cell;
    float wv = W[(size_t)(i0 + il) * MCOLS + j0 + c];
    w[cell] = wv;
    fwd[cell] = (sColS[c] - wv) * (1.0f / (float)(NROWS - 1));
    bwd[cell] = (rowS[i0 + il] - wv) * (1.0f / (float)(MCOLS - 1));
  }

  float h1[4][10];
#pragma unroll
  for (int o = 0; o < 10; ++o) {
    float w1a = sW1[o], w1b = sW1[10 + o], w1c = sW1[20 + o], bb = sb1[o];
#pragma unroll
    for (int cell = 0; cell < 4; ++cell) {
      float v = fmaf(w[cell], w1a, fmaf(fwd[cell], w1b, fmaf(bwd[cell], w1c, bb)));
      h1[cell][o] = fmaxf(v, 0.f);
    }
  }
  float u[4] = {sb3, sb3, sb3, sb3};
#pragma unroll
  for (int o = 0; o < 10; ++o) {
    float h2[4];
    float bb = sb2[o];
#pragma unroll
    for (int cell = 0; cell < 4; ++cell) h2[cell] = bb;
#pragma unroll
    for (int p = 0; p < 10; ++p) {
      float wv = sW2[p * 10 + o];
#pragma unroll
      for (int cell = 0; cell < 4; ++cell) h2[cell] = fmaf(h1[cell][p], wv, h2[cell]);
    }
    float w3 = sW3[o];
#pragma unroll
    for (int cell = 0; cell < 4; ++cell) u[cell] = fmaf(fmaxf(h2[cell], 0.f), w3, u[cell]);
  }

#pragma unroll
  for (int cell = 0; cell < 4; ++cell) {
    int il = r + 8 * cell;
    float nw = w[cell] + u[cell];
    unsigned short hb = f2bf_rne(nw);
    Th[il][c] = hb;
    Tl[il][c] = f2bf_rne(nw - bf2f(hb));
  }
  __syncthreads();

#pragma unroll
  for (int cell = 0; cell < 4; ++cell) {
    int jl = r + 8 * cell;
    size_t oidx = (size_t)(j0 + jl) * NROWS + i0 + c;
    Bth[oidx] = Th[c][jl];
    Btl[oidx] = Tl[c][jl];
  }
}

// ---------------- 3-term bf16 MFMA GEMM -------------------------------------
// Staging (per 16-row block R): lane l fetches global
//   row = R*16 + (l>>2), kchunk = (l&3) ^ ((l>>3)&3)   (8 bf16 = 16B)
// -> each quad of lanes covers one contiguous 64B row segment (round-3
//    coalescing), LDS dest is linear (global_load_lds constraint).
// LDS slot s in block R therefore holds (row = s>>2, kchunk = (s&3)^((s>>3)&3)).
// Fragment read: lane l needs (row = l&15, kchunk = l>>4)
//   -> slot s = 4*(l&15) + ((l>>4) ^ ((l>>1)&3))
// Per 16-lane phase, s mod 8 covers all 8 four-bank groups exactly twice:
// 2-way aliasing = free. Loop-invariant per lane.
__global__ __launch_bounds__(256) void gemm_kernel(
    const unsigned short* __restrict__ Xh, const unsigned short* __restrict__ Xl,
    const unsigned short* __restrict__ Bth, const unsigned short* __restrict__ Btl,
    float* __restrict__ C) {
  __shared__ short sAh[128 * 32];
  __shared__ short sAl[128 * 32];
  __shared__ short sBh[128 * 32];
  __shared__ short sBl[128 * 32];

  const int tid = threadIdx.x;
  const int lane = tid & 63;
  const int wave = tid >> 6;
  const int wr = wave >> 1;
  const int wc = wave & 1;
  const int fm = lane & 15;
  const int q = lane >> 4;

  const int bx = blockIdx.x;
  const int by = blockIdx.y;

  const unsigned short* A0h = Xh + (size_t)(by * 128) * GK;
  const unsigned short* A0l = Xl + (size_t)(by * 128) * GK;
  const unsigned short* B0h = Bth + (size_t)(bx * 128) * GK;
  const unsigned short* B0l = Btl + (size_t)(bx * 128) * GK;

  // staging address components (per lane, loop-invariant)
  const int srow = lane >> 2;                          // 0..15
  const int skof = ((lane & 3) ^ ((lane >> 3) & 3)) * 8;  // swizzled k-chunk

  // fragment read slot (per lane, loop-invariant)
  const int sfrag = 4 * fm + (q ^ ((lane >> 1) & 3));  // 0..63

  floatx4 acc[4][4];
#pragma unroll
  for (int i = 0; i < 4; ++i)
#pragma unroll
    for (int j = 0; j < 4; ++j) acc[i][j] = (floatx4){0.f, 0.f, 0.f, 0.f};

  for (int k0 = 0; k0 < GK; k0 += 32) {
#pragma unroll
    for (int r = 0; r < 2; ++r) {
      int R = wave * 2 + r;                       // 16-row block 0..7
      size_t goff = (size_t)(R * 16 + srow) * GK + k0 + skof;
      int ldsoff = R * 512;                       // shorts (1KB per block)
      __builtin_amdgcn_global_load_lds(
          (const __attribute__((address_space(1))) void*)(A0h + goff),
          (__attribute__((address_space(3))) void*)(sAh + ldsoff), 16, 0, 0);
      __builtin_amdgcn_global_load_lds(
          (const __attribute__((address_space(1))) void*)(A0l + goff),
          (__attribute__((address_space(3))) void*)(sAl + ldsoff), 16, 0, 0);
      __builtin_amdgcn_global_load_lds(
          (const __attribute__((address_space(1))) void*)(B0h + goff),
          (__attribute__((address_space(3))) void*)(sBh + ldsoff), 16, 0, 0);
      __builtin_amdgcn_global_load_lds(
          (const __attribute__((address_space(1))) void*)(B0l + goff),
          (__attribute__((address_space(3))) void*)(sBl + ldsoff), 16, 0, 0);
    }
    __syncthreads();

    short8 ah[4], al[4], bh[4], bl[4];
#pragma unroll
    for (int mi = 0; mi < 4; ++mi) {
      int off = (wr * 4 + mi) * 512 + sfrag * 8;
      ah[mi] = *(const short8*)(sAh + off);
      al[mi] = *(const short8*)(sAl + off);
    }
#pragma unroll
    for (int ni = 0; ni < 4; ++ni) {
      int off = (wc * 4 + ni) * 512 + sfrag * 8;
      bh[ni] = *(const short8*)(sBh + off);
      bl[ni] = *(const short8*)(sBl + off);
    }
#pragma unroll
    for (int mi = 0; mi < 4; ++mi)
#pragma unroll
      for (int ni = 0; ni < 4; ++ni) {
        acc[mi][ni] = __builtin_amdgcn_mfma_f32_16x16x32_bf16(ah[mi], bh[ni], acc[mi][ni], 0, 0, 0);
        acc[mi][ni] = __builtin_amdgcn_mfma_f32_16x16x32_bf16(al[mi], bh[ni], acc[mi][ni], 0, 0, 0);
        acc[mi][ni] = __builtin_amdgcn_mfma_f32_16x16x32_bf16(ah[mi], bl[ni], acc[mi][ni], 0, 0, 0);
      }
    __syncthreads();
  }

#pragma unroll
  for (int mi = 0; mi < 4; ++mi)
#pragma unroll
    for (int ni = 0; ni < 4; ++ni) {
      int col = bx * 128 + wc * 64 + ni * 16 + fm;
#pragma unroll
      for (int r = 0; r < 4; ++r) {
        int row = by * 128 + wr * 64 + mi * 16 + q * 4 + r;
        C[(size_t)row * 2048 + col] = acc[mi][ni][r];
      }
    }
}

// ---------------- row softmax in place (wave-shuffle reductions) ------------
__global__ __launch_bounds__(256) void softmax_kernel(float* __restrict__ C) {
  const int row = blockIdx.x;
  const int tid = threadIdx.x;
  const int lane = tid & 63;
  const int wv = tid >> 6;
  float4* p = (float4*)(C + (size_t)row * MCOLS);
  float4 a = p[tid];
  float4 b = p[tid + 256];

  __shared__ float wmax[4], wsum[4];

  float vmax = fmaxf(fmaxf(fmaxf(a.x, a.y), fmaxf(a.z, a.w)),
                     fmaxf(fmaxf(b.x, b.y), fmaxf(b.z, b.w)));
#pragma unroll
  for (int off = 32; off > 0; off >>= 1)
    vmax = fmaxf(vmax, __shfl_xor(vmax, off));
  if (lane == 0) wmax[wv] = vmax;
  __syncthreads();
  float m = fmaxf(fmaxf(wmax[0], wmax[1]), fmaxf(wmax[2], wmax[3]));

  float e[8];
  e[0] = __expf(a.x - m); e[1] = __expf(a.y - m); e[2] = __expf(a.z - m); e[3] = __expf(a.w - m);
  e[4] = __expf(b.x - m); e[5] = __expf(b.y - m); e[6] = __expf(b.z - m); e[7] = __expf(b.w - m);
  float sum = ((e[0] + e[1]) + (e[2] + e[3])) + ((e[4] + e[5]) + (e[6] + e[7]));
#pragma unroll
  for (int off = 32; off > 0; off >>= 1)
    sum += __shfl_xor(sum, off);
  if (lane == 0) wsum[wv] = sum;
  __syncthreads();
  float inv = 1.0f / (((wsum[0] + wsum[1]) + (wsum[2] + wsum[3])));

  a = make_float4(e[0] * inv, e[1] * inv, e[2] * inv, e[3] * inv);
  b = make_float4(e[4] * inv, e[5] * inv, e[6] * inv, e[7] * inv);
  p[tid] = a;
  p[tid + 256] = b;
}

// ---------------- launcher --------------------------------------------------
extern "C" void kernel_launch(void* const* d_in, const int* in_sizes, int n_in,
                              void* d_out, int out_size, void* d_ws, size_t ws_size,
                              hipStream_t stream) {
  const float* X      = (const float*)d_in[0];
  const float* weight = (const float*)d_in[1];
  const float* W1     = (const float*)d_in[2];
  const float* b1     = (const float*)d_in[3];
  const float* W2     = (const float*)d_in[4];
  const float* b2     = (const float*)d_in[5];
  const float* W3     = (const float*)d_in[6];
  const float* b3     = (const float*)d_in[7];
  float* out = (float*)d_out;

  const int N = 2048, M = 2048;
  const int Bdim = in_sizes[0] / N;   // 8192

  float* rowS = (float*)d_ws;
  float* part = rowS + 2048;
  unsigned short* Xh  = (unsigned short*)(part + NCHUNK * 2048);
  unsigned short* Xl  = Xh + (size_t)Bdim * N;
  unsigned short* Bth = Xl + (size_t)Bdim * N;
  unsigned short* Btl = Bth + (size_t)M * N;

  const int conv_blocks = (Bdim * N) / 4 / 256;  // 16384
  pre_kernel<<<CS_BLOCKS + RS_BLOCKS + conv_blocks, 256, 0, stream>>>(
      X, weight, Xh, Xl, part, rowS);

  nca_update_kernel<<<dim3(M / 32, N / 32), 256, 0, stream>>>(
      weight, part, rowS, W1, b1, W2, b2, W3, b3, Bth, Btl);

  gemm_kernel<<<dim3(M / 128, Bdim / 128), 256, 0, stream>>>(Xh, Xl, Bth, Btl, out);

  softmax_kernel<<<Bdim, 256, 0, stream>>>(out);
}